// Round 7
// baseline (1054.176 us; speedup 1.0000x reference)
//
#include <hip/hip_runtime.h>
#include <hip/hip_bf16.h>
#include <math.h>

// S=4096, D=512, H=8, hd=64, F=2048, E=8, top-2. I/O fp32.
// Attention path: split-bf16 (hi+lo, 3-MFMA) emulated fp32 => fp32-faithful
// routing. MoE: sparse top-2, all experts in one launch, atomic scatter-add.
#define SQ   4096
#define DM   512
#define NH   8
#define HDIM 64
#define FF   2048
#define NE   8

typedef unsigned short u16;
typedef unsigned int   u32;
typedef __attribute__((ext_vector_type(8))) __bf16 bf16x8;
typedef __attribute__((ext_vector_type(4))) float  f32x4;

__device__ __forceinline__ float bf2f(u16 v) {
    union { u32 i; float f; } c; c.i = ((u32)v) << 16; return c.f;
}
__device__ __forceinline__ u16 f2bf(float f) {  // RNE
    union { float f; u32 i; } c; c.f = f; u32 u = c.i;
    return (u16)((u + 0x7fffu + ((u >> 16) & 1u)) >> 16);
}
// Truncation split: v = hi + r exactly, lo = trunc-bf16(r). 4 VALU ops.
__device__ __forceinline__ void tsplit(float v, u16& hi, u16& lo) {
    u32 vb = __float_as_uint(v);
    u32 hb = vb & 0xFFFF0000u;
    float r = v - __uint_as_float(hb);
    hi = (u16)(hb >> 16);
    lo = (u16)(__float_as_uint(r) >> 16);
}

#define BM 128
#define BN 128
#define BK 32
#define BKP 40   // padded LDS row stride (2-way on frag reads -> free)

// ===========================================================================
// Split-bf16 GEMM: C = (Ahi+Alo)@(Bhi+Blo)^T + bias. 3 MFMAs (hh+hl+lh).
// mode 0: split bf16 pair out. mode 1: fp32 out (+resid).
// ===========================================================================
__global__ __launch_bounds__(256) void gemm_split(
    const u16* __restrict__ Ahi, const u16* __restrict__ Alo, int lda,
    const u16* __restrict__ Bhi, const u16* __restrict__ Blo, int ldb,
    int M, int N, int K,
    const float* __restrict__ bias,
    const float* __restrict__ resid, int ldres,
    u16* __restrict__ Chi, u16* __restrict__ Clo,
    float* __restrict__ Cf, int ldc, int mode)
{
    __shared__ __align__(16) u16 Ash[BM * BKP], Asl[BM * BKP];
    __shared__ __align__(16) u16 Bsh[BN * BKP], Bsl[BN * BKP];
    const int tid  = threadIdx.x;
    const int wave = tid >> 6;
    const int lane = tid & 63;
    const int quad = lane >> 4;
    const int l16  = lane & 15;
    const int bm = blockIdx.x * BM;
    const int bn = blockIdx.y * BN;
    const int wm = (wave & 1) * 64;
    const int wn = (wave >> 1) * 64;

    f32x4 acc[4][4];
#pragma unroll
    for (int i = 0; i < 4; i++)
#pragma unroll
        for (int j = 0; j < 4; j++)
#pragma unroll
            for (int r = 0; r < 4; r++) acc[i][j][r] = 0.0f;

    for (int k0 = 0; k0 < K; k0 += BK) {
#pragma unroll
        for (int i = 0; i < 2; i++) {
            int c = tid + i * 256;
            int row = c >> 2;
            int col = (c & 3) << 3;
            int ga = bm + row, gb2 = bn + row;
            uint4 vah = make_uint4(0u,0u,0u,0u), val = vah, vbh = vah, vbl = vah;
            if (ga < M) {
                vah = *(const uint4*)(Ahi + (size_t)ga * lda + k0 + col);
                val = *(const uint4*)(Alo + (size_t)ga * lda + k0 + col);
            }
            if (gb2 < N) {
                vbh = *(const uint4*)(Bhi + (size_t)gb2 * ldb + k0 + col);
                vbl = *(const uint4*)(Blo + (size_t)gb2 * ldb + k0 + col);
            }
            *(uint4*)(Ash + row * BKP + col) = vah;
            *(uint4*)(Asl + row * BKP + col) = val;
            *(uint4*)(Bsh + row * BKP + col) = vbh;
            *(uint4*)(Bsl + row * BKP + col) = vbl;
        }
        __syncthreads();
        bf16x8 ah[4], al[4], bh[4], bl[4];
#pragma unroll
        for (int i = 0; i < 4; i++) {
            ah[i] = *(const bf16x8*)(Ash + (wm + i * 16 + l16) * BKP + quad * 8);
            al[i] = *(const bf16x8*)(Asl + (wm + i * 16 + l16) * BKP + quad * 8);
        }
#pragma unroll
        for (int j = 0; j < 4; j++) {
            bh[j] = *(const bf16x8*)(Bsh + (wn + j * 16 + l16) * BKP + quad * 8);
            bl[j] = *(const bf16x8*)(Bsl + (wn + j * 16 + l16) * BKP + quad * 8);
        }
#pragma unroll
        for (int i = 0; i < 4; i++)
#pragma unroll
            for (int j = 0; j < 4; j++) {
                acc[i][j] = __builtin_amdgcn_mfma_f32_16x16x32_bf16(ah[i], bh[j], acc[i][j], 0,0,0);
                acc[i][j] = __builtin_amdgcn_mfma_f32_16x16x32_bf16(ah[i], bl[j], acc[i][j], 0,0,0);
                acc[i][j] = __builtin_amdgcn_mfma_f32_16x16x32_bf16(al[i], bh[j], acc[i][j], 0,0,0);
            }
        __syncthreads();
    }

#pragma unroll
    for (int i = 0; i < 4; i++)
#pragma unroll
        for (int j = 0; j < 4; j++)
#pragma unroll
            for (int r = 0; r < 4; r++) {
                int row = bm + wm + i * 16 + quad * 4 + r;
                int col = bn + wn + j * 16 + l16;
                if (row >= M || col >= N) continue;
                float v = acc[i][j][r] + (bias ? bias[col] : 0.0f);
                size_t idx = (size_t)row * ldc + col;
                if (mode == 0) {
                    u16 hb, lb;
                    tsplit(v, hb, lb);
                    Chi[idx] = hb;
                    Clo[idx] = lb;
                } else {
                    if (resid) v += resid[(size_t)row * ldres + col];
                    Cf[idx] = v;
                }
            }
}

// Inline expert lookup from cnt (128-aligned packing), replaces make_off.
__device__ __forceinline__ int find_expert(const int* __restrict__ cnt,
                                           int bmg, int& bml, int& obase)
{
    int a = 0;
#pragma unroll
    for (int e = 0; e < NE; e++) {
        int pad = ((cnt[e] + 127) >> 7) << 7;
        if (bmg < a + pad) { bml = bmg - a; obase = a; return e; }
        a += pad;
    }
    return -1;
}

// ===========================================================================
// MoE all-expert fused w1/w2 GEMM: h = silu(x@w1^T+b1)*(x@w2^T+b2)
// grid (72, 16). A rows gathered via idxl; B staged fp32->bf16 inline.
// ===========================================================================
__global__ __launch_bounds__(256) void moe12_all(
    const u16* __restrict__ A, int lda,
    const int* __restrict__ idxl, const int* __restrict__ cnt,
    const float* __restrict__ w1, const float* __restrict__ b1,
    const float* __restrict__ w2, const float* __restrict__ b2,
    u16* __restrict__ H)
{
    const int bmg = blockIdx.x * BM;
    int bml, obase;
    int e = find_expert(cnt, bmg, bml, obase);
    if (e < 0) return;
    const int M = cnt[e];
    if (bml >= M) return;
    const float* B1 = w1 + (size_t)e * FF * DM;
    const float* B2 = w2 + (size_t)e * FF * DM;
    const int*   rl = idxl + e * SQ;

    __shared__ __align__(16) u16 As[BM * BKP], Bs1[BN * BKP], Bs2[BN * BKP];
    const int tid  = threadIdx.x;
    const int wave = tid >> 6;
    const int lane = tid & 63;
    const int quad = lane >> 4;
    const int l16  = lane & 15;
    const int bn = blockIdx.y * BN;
    const int wm = (wave & 1) * 64;
    const int wn = (wave >> 1) * 64;

    f32x4 acc1[4][4], acc2[4][4];
#pragma unroll
    for (int i = 0; i < 4; i++)
#pragma unroll
        for (int j = 0; j < 4; j++)
#pragma unroll
            for (int r = 0; r < 4; r++) { acc1[i][j][r] = 0.0f; acc2[i][j][r] = 0.0f; }

    for (int k0 = 0; k0 < DM; k0 += BK) {
#pragma unroll
        for (int i = 0; i < 2; i++) {
            int c = tid + i * 256;
            int row = c >> 2;
            int col = (c & 3) << 3;
            uint4 va = make_uint4(0u,0u,0u,0u);
            int lr = bml + row;
            if (lr < M) {
                int ar = rl[lr];
                va = *(const uint4*)(A + (size_t)ar * lda + k0 + col);
            }
            *(uint4*)(As + row * BKP + col) = va;
        }
#pragma unroll
        for (int i = 0; i < 4; i++) {
            int c = tid + i * 256;
            int row = c >> 3;
            int col = (c & 7) << 2;
            float4 v1 = *(const float4*)(B1 + (size_t)(bn + row) * DM + k0 + col);
            float4 v2 = *(const float4*)(B2 + (size_t)(bn + row) * DM + k0 + col);
            ushort4 h1, h2;
            h1.x = f2bf(v1.x); h1.y = f2bf(v1.y); h1.z = f2bf(v1.z); h1.w = f2bf(v1.w);
            h2.x = f2bf(v2.x); h2.y = f2bf(v2.y); h2.z = f2bf(v2.z); h2.w = f2bf(v2.w);
            *(ushort4*)(Bs1 + row * BKP + col) = h1;
            *(ushort4*)(Bs2 + row * BKP + col) = h2;
        }
        __syncthreads();
        bf16x8 af[4], b1f[4], b2f[4];
#pragma unroll
        for (int i = 0; i < 4; i++)
            af[i] = *(const bf16x8*)(As + (wm + i * 16 + l16) * BKP + quad * 8);
#pragma unroll
        for (int j = 0; j < 4; j++) {
            b1f[j] = *(const bf16x8*)(Bs1 + (wn + j * 16 + l16) * BKP + quad * 8);
            b2f[j] = *(const bf16x8*)(Bs2 + (wn + j * 16 + l16) * BKP + quad * 8);
        }
#pragma unroll
        for (int i = 0; i < 4; i++)
#pragma unroll
            for (int j = 0; j < 4; j++) {
                acc1[i][j] = __builtin_amdgcn_mfma_f32_16x16x32_bf16(af[i], b1f[j], acc1[i][j], 0,0,0);
                acc2[i][j] = __builtin_amdgcn_mfma_f32_16x16x32_bf16(af[i], b2f[j], acc2[i][j], 0,0,0);
            }
        __syncthreads();
    }

#pragma unroll
    for (int i = 0; i < 4; i++)
#pragma unroll
        for (int j = 0; j < 4; j++)
#pragma unroll
            for (int r = 0; r < 4; r++) {
                int rowl = bml + wm + i * 16 + quad * 4 + r;
                if (rowl >= M) continue;
                int col = bn + wn + j * 16 + l16;
                float g1 = acc1[i][j][r] + b1[e * FF + col];
                float g2 = acc2[i][j][r] + b2[e * FF + col];
                float s  = g1 / (1.0f + __expf(-g1));
                H[(size_t)(obase + rowl) * FF + col] = f2bf(s * g2);
            }
}

// ===========================================================================
// MoE all-expert down-proj: out[tok] += cw*(h@wo^T + bo). grid (72, 4).
// ===========================================================================
__global__ __launch_bounds__(256) void moe_y_all(
    const u16* __restrict__ H,
    const float* __restrict__ wo, const float* __restrict__ bo,
    const int* __restrict__ idxl, const float* __restrict__ cw,
    const int* __restrict__ cnt,
    float* __restrict__ out)
{
    const int bmg = blockIdx.x * BM;
    int bml, obase;
    int e = find_expert(cnt, bmg, bml, obase);
    if (e < 0) return;
    const int M = cnt[e];
    if (bml >= M) return;
    const float* B = wo + (size_t)e * DM * FF;

    __shared__ __align__(16) u16 As[BM * BKP], Bs[BN * BKP];
    const int tid  = threadIdx.x;
    const int wave = tid >> 6;
    const int lane = tid & 63;
    const int quad = lane >> 4;
    const int l16  = lane & 15;
    const int bn = blockIdx.y * BN;
    const int wm = (wave & 1) * 64;
    const int wn = (wave >> 1) * 64;

    f32x4 acc[4][4];
#pragma unroll
    for (int i = 0; i < 4; i++)
#pragma unroll
        for (int j = 0; j < 4; j++)
#pragma unroll
            for (int r = 0; r < 4; r++) acc[i][j][r] = 0.0f;

    for (int k0 = 0; k0 < FF; k0 += BK) {
#pragma unroll
        for (int i = 0; i < 2; i++) {
            int c = tid + i * 256;
            int row = c >> 2;
            int col = (c & 3) << 3;
            uint4 va = *(const uint4*)(H + (size_t)(bmg + row) * FF + k0 + col);
            *(uint4*)(As + row * BKP + col) = va;
        }
#pragma unroll
        for (int i = 0; i < 4; i++) {
            int c = tid + i * 256;
            int row = c >> 3;
            int col = (c & 7) << 2;
            float4 v = *(const float4*)(B + (size_t)(bn + row) * FF + k0 + col);
            ushort4 h;
            h.x = f2bf(v.x); h.y = f2bf(v.y); h.z = f2bf(v.z); h.w = f2bf(v.w);
            *(ushort4*)(Bs + row * BKP + col) = h;
        }
        __syncthreads();
        bf16x8 af[4], bf[4];
#pragma unroll
        for (int i = 0; i < 4; i++)
            af[i] = *(const bf16x8*)(As + (wm + i * 16 + l16) * BKP + quad * 8);
#pragma unroll
        for (int j = 0; j < 4; j++)
            bf[j] = *(const bf16x8*)(Bs + (wn + j * 16 + l16) * BKP + quad * 8);
#pragma unroll
        for (int i = 0; i < 4; i++)
#pragma unroll
            for (int j = 0; j < 4; j++)
                acc[i][j] = __builtin_amdgcn_mfma_f32_16x16x32_bf16(af[i], bf[j], acc[i][j], 0,0,0);
        __syncthreads();
    }

#pragma unroll
    for (int i = 0; i < 4; i++)
#pragma unroll
        for (int j = 0; j < 4; j++)
#pragma unroll
            for (int r = 0; r < 4; r++) {
                int rowl = bml + wm + i * 16 + quad * 4 + r;
                if (rowl >= M) continue;
                int col = bn + wn + j * 16 + l16;
                int tok = idxl[e * SQ + rowl];
                float wgt = cw[e * SQ + rowl];
                atomicAdd(out + (size_t)tok * DM + col,
                          wgt * (acc[i][j][r] + bo[e * DM + col]));
            }
}

// ===========================================================================
// Flash attention, split precision. 64-row Q tiles, grid (64, 8), 256 thr.
// Register-prefetched K/V staging; raw-domain max + fma-folded exp2 scale;
// truncation hi/lo splits. Wave-private P buffer (no mid-tile barrier).
// ===========================================================================
#define KP 72
#define SCL 0.18033688011112042f   // 0.125 * log2(e)
__global__ __launch_bounds__(256) void flash_attn(
    const u16* __restrict__ qh, const u16* __restrict__ ql,   // [4096,1536]
    const u16* __restrict__ vth, const u16* __restrict__ vtl, // [512,4096]
    u16* __restrict__ oh, u16* __restrict__ ol)               // [4096,512]
{
    __shared__ __align__(16) u16 Ksh[64*KP], Ksl[64*KP], Vsh[64*KP], Vsl[64*KP];
    __shared__ __align__(16) u16 Psh[4][16*KP], Psl[4][16*KP];
    const int tid  = threadIdx.x;
    const int wave = tid >> 6;
    const int lane = tid & 63;
    const int quad = lane >> 4;
    const int l16  = lane & 15;
    const int h    = blockIdx.y;
    const int qbase = blockIdx.x * 64 + wave * 16;
    const int NT = SQ / 64;

    bf16x8 aqh[2], aql[2];
#pragma unroll
    for (int kk = 0; kk < 2; kk++) {
        size_t off = (size_t)(qbase + l16) * (3*DM) + h*HDIM + kk*32 + quad*8;
        aqh[kk] = *(const bf16x8*)(qh + off);
        aql[kk] = *(const bf16x8*)(ql + off);
    }

    // staging addresses for this thread (2 chunks x 4 arrays)
    int r0[2], co[2];
#pragma unroll
    for (int i = 0; i < 2; i++) {
        int c = tid + i * 256;
        r0[i] = c >> 3;
        co[i] = (c & 7) << 3;
    }

    float m_[4], l_[4];
    f32x4 o_[4];
#pragma unroll
    for (int r = 0; r < 4; r++) { m_[r] = -1e30f; l_[r] = 0.0f; }
#pragma unroll
    for (int nd = 0; nd < 4; nd++)
#pragma unroll
        for (int r = 0; r < 4; r++) o_[nd][r] = 0.0f;

    // prefetch tile 0
    uint4 pre[8];
#pragma unroll
    for (int i = 0; i < 2; i++) {
        size_t koff = (size_t)(r0[i]) * (3*DM) + DM + h*HDIM + co[i];
        size_t voff = (size_t)(h*HDIM + r0[i]) * SQ + co[i];
        pre[i*4+0] = *(const uint4*)(qh  + koff);
        pre[i*4+1] = *(const uint4*)(ql  + koff);
        pre[i*4+2] = *(const uint4*)(vth + voff);
        pre[i*4+3] = *(const uint4*)(vtl + voff);
    }

    for (int jt = 0; jt < NT; jt++) {
        // write prefetched tile to LDS
#pragma unroll
        for (int i = 0; i < 2; i++) {
            *(uint4*)(Ksh + r0[i]*KP + co[i]) = pre[i*4+0];
            *(uint4*)(Ksl + r0[i]*KP + co[i]) = pre[i*4+1];
            *(uint4*)(Vsh + r0[i]*KP + co[i]) = pre[i*4+2];
            *(uint4*)(Vsl + r0[i]*KP + co[i]) = pre[i*4+3];
        }
        __syncthreads();
        // prefetch next tile (overlaps this tile's compute)
        if (jt + 1 < NT) {
#pragma unroll
            for (int i = 0; i < 2; i++) {
                size_t koff = (size_t)((jt+1)*64 + r0[i]) * (3*DM) + DM + h*HDIM + co[i];
                size_t voff = (size_t)(h*HDIM + r0[i]) * SQ + (jt+1)*64 + co[i];
                pre[i*4+0] = *(const uint4*)(qh  + koff);
                pre[i*4+1] = *(const uint4*)(ql  + koff);
                pre[i*4+2] = *(const uint4*)(vth + voff);
                pre[i*4+3] = *(const uint4*)(vtl + voff);
            }
        }

        f32x4 s[4];
#pragma unroll
        for (int jn = 0; jn < 4; jn++) {
            f32x4 z;
#pragma unroll
            for (int r = 0; r < 4; r++) z[r] = 0.0f;
#pragma unroll
            for (int kk = 0; kk < 2; kk++) {
                bf16x8 kh = *(const bf16x8*)(Ksh + (jn*16 + l16)*KP + kk*32 + quad*8);
                bf16x8 kl = *(const bf16x8*)(Ksl + (jn*16 + l16)*KP + kk*32 + quad*8);
                z = __builtin_amdgcn_mfma_f32_16x16x32_bf16(aqh[kk], kh, z, 0,0,0);
                z = __builtin_amdgcn_mfma_f32_16x16x32_bf16(aqh[kk], kl, z, 0,0,0);
                z = __builtin_amdgcn_mfma_f32_16x16x32_bf16(aql[kk], kh, z, 0,0,0);
            }
            s[jn] = z;   // raw scores (scale folded into exp2 below)
        }

        float mx[4], al2[4], rs[4], nscl[4];
#pragma unroll
        for (int r = 0; r < 4; r++)
            mx[r] = fmaxf(fmaxf(s[0][r], s[1][r]), fmaxf(s[2][r], s[3][r]));
#pragma unroll
        for (int r = 0; r < 4; r++) {
#pragma unroll
            for (int o2 = 1; o2 < 16; o2 <<= 1)
                mx[r] = fmaxf(mx[r], __shfl_xor(mx[r], o2));
            float nm = fmaxf(m_[r], mx[r]);
            al2[r] = exp2f((m_[r] - nm) * SCL);
            m_[r] = nm;
            nscl[r] = nm * SCL;
            rs[r] = 0.0f;
        }
#pragma unroll
        for (int jn = 0; jn < 4; jn++)
#pragma unroll
            for (int r = 0; r < 4; r++) {
                float p = exp2f(fmaf(s[jn][r], SCL, -nscl[r]));
                s[jn][r] = p;
                rs[r] += p;
            }
#pragma unroll
        for (int r = 0; r < 4; r++) {
#pragma unroll
            for (int o2 = 1; o2 < 16; o2 <<= 1)
                rs[r] += __shfl_xor(rs[r], o2);
            l_[r] = l_[r] * al2[r] + rs[r];
        }
#pragma unroll
        for (int nd = 0; nd < 4; nd++)
#pragma unroll
            for (int r = 0; r < 4; r++) o_[nd][r] *= al2[r];
#pragma unroll
        for (int jn = 0; jn < 4; jn++)
#pragma unroll
            for (int r = 0; r < 4; r++) {
                u16 ph, pl;
                tsplit(s[jn][r], ph, pl);
                int pidx = (quad*4 + r)*KP + jn*16 + l16;
                Psh[wave][pidx] = ph;
                Psl[wave][pidx] = pl;
            }
        // no barrier: Ps is wave-private; per-wave DS ops execute in order

        bf16x8 php[2], plp[2];
#pragma unroll
        for (int kk = 0; kk < 2; kk++) {
            php[kk] = *(const bf16x8*)(Psh[wave] + l16*KP + kk*32 + quad*8);
            plp[kk] = *(const bf16x8*)(Psl[wave] + l16*KP + kk*32 + quad*8);
        }
#pragma unroll
        for (int nd = 0; nd < 4; nd++) {
#pragma unroll
            for (int kk = 0; kk < 2; kk++) {
                bf16x8 vh = *(const bf16x8*)(Vsh + (nd*16 + l16)*KP + kk*32 + quad*8);
                bf16x8 vl = *(const bf16x8*)(Vsl + (nd*16 + l16)*KP + kk*32 + quad*8);
                o_[nd] = __builtin_amdgcn_mfma_f32_16x16x32_bf16(php[kk], vh, o_[nd], 0,0,0);
                o_[nd] = __builtin_amdgcn_mfma_f32_16x16x32_bf16(php[kk], vl, o_[nd], 0,0,0);
                o_[nd] = __builtin_amdgcn_mfma_f32_16x16x32_bf16(plp[kk], vh, o_[nd], 0,0,0);
            }
        }
        __syncthreads();   // before next tile overwrites Ks/Vs
    }

#pragma unroll
    for (int nd = 0; nd < 4; nd++)
#pragma unroll
        for (int r = 0; r < 4; r++) {
            int row = qbase + quad*4 + r;
            int col = h*HDIM + nd*16 + l16;
            float w = o_[nd][r] / l_[r];
            u16 hb, lb;
            tsplit(w, hb, lb);
            oh[(size_t)row * DM + col] = hb;
            ol[(size_t)row * DM + col] = lb;
        }
}

// LN1: fp32 in -> split bf16 pair out.
__global__ __launch_bounds__(256) void ln1_split(
    const float* __restrict__ x, const float* __restrict__ g,
    const float* __restrict__ b, u16* __restrict__ ohi, u16* __restrict__ olo)
{
    const int row = blockIdx.x;
    const int tid = threadIdx.x;
    float v0 = x[(size_t)row * DM + tid];
    float v1 = x[(size_t)row * DM + tid + 256];
    float s = v0 + v1, sq = v0*v0 + v1*v1;
#pragma unroll
    for (int o = 1; o < 64; o <<= 1) { s += __shfl_xor(s, o); sq += __shfl_xor(sq, o); }
    __shared__ float ss[4], ssq[4];
    if ((tid & 63) == 0) { ss[tid>>6] = s; ssq[tid>>6] = sq; }
    __syncthreads();
    s  = ss[0]+ss[1]+ss[2]+ss[3];
    sq = ssq[0]+ssq[1]+ssq[2]+ssq[3];
    float m = s * (1.0f/DM);
    float rstd = rsqrtf(sq*(1.0f/DM) - m*m + 1e-5f);
    float y0 = (v0-m)*rstd*g[tid]     + b[tid];
    float y1 = (v1-m)*rstd*g[tid+256] + b[tid+256];
    u16 h0, l0, h1, l1;
    tsplit(y0, h0, l0);
    tsplit(y1, h1, l1);
    ohi[(size_t)row*DM + tid]       = h0;  olo[(size_t)row*DM + tid]       = l0;
    ohi[(size_t)row*DM + tid + 256] = h1;  olo[(size_t)row*DM + tid + 256] = l1;
}

// LN2: fp32 in -> plain bf16 out. Block 0 also zeroes the routing counters.
__global__ __launch_bounds__(256) void ln_kernel(
    const float* __restrict__ x, const float* __restrict__ g,
    const float* __restrict__ b, u16* __restrict__ out, int* __restrict__ cnt)
{
    const int row = blockIdx.x;
    const int tid = threadIdx.x;
    if (row == 0 && tid < NE) cnt[tid] = 0;
    float v0 = x[(size_t)row * DM + tid];
    float v1 = x[(size_t)row * DM + tid + 256];
    float s = v0 + v1, sq = v0*v0 + v1*v1;
#pragma unroll
    for (int o = 1; o < 64; o <<= 1) { s += __shfl_xor(s, o); sq += __shfl_xor(sq, o); }
    __shared__ float ss[4], ssq[4];
    if ((tid & 63) == 0) { ss[tid>>6] = s; ssq[tid>>6] = sq; }
    __syncthreads();
    s  = ss[0]+ss[1]+ss[2]+ss[3];
    sq = ssq[0]+ssq[1]+ssq[2]+ssq[3];
    float m = s * (1.0f/DM);
    float rstd = rsqrtf(sq*(1.0f/DM) - m*m + 1e-5f);
    out[(size_t)row*DM + tid]       = f2bf((v0-m)*rstd*g[tid]     + b[tid]);
    out[(size_t)row*DM + tid + 256] = f2bf((v1-m)*rstd*g[tid+256] + b[tid+256]);
}

// Coalesced V transpose via LDS 64x64 tiles (pad 66: both phases conflict-free)
__global__ __launch_bounds__(256) void transpose_v2(
    const u16* __restrict__ qh, const u16* __restrict__ ql,
    u16* __restrict__ vth, u16* __restrict__ vtl)
{
    __shared__ u16 Th[64 * 66], Tl[64 * 66];
    const int t0  = blockIdx.x * 64;
    const int hd0 = blockIdx.y * 64;
    const int tid = threadIdx.x;
#pragma unroll
    for (int k = 0; k < 16; k++) {
        int idx = tid + k * 256;
        int r = idx >> 6, j = idx & 63;
        size_t src = (size_t)(t0 + r) * (3*DM) + 2*DM + hd0 + j;
        Th[r * 66 + j] = qh[src];
        Tl[r * 66 + j] = ql[src];
    }
    __syncthreads();
#pragma unroll
    for (int k = 0; k < 16; k++) {
        int idx = tid + k * 256;
        int r = idx >> 6, c2 = idx & 63;
        size_t dst = (size_t)(hd0 + r) * SQ + t0 + c2;
        vth[dst] = Th[c2 * 66 + r];
        vtl[dst] = Tl[c2 * 66 + r];
    }
}

// Gate (own fp32 LN2) + top-2 compaction into per-expert lists.
__global__ __launch_bounds__(256) void gate_route(
    const float* __restrict__ x1, const float* __restrict__ g,
    const float* __restrict__ b, const float* __restrict__ gw,
    const float* __restrict__ gb,
    int* __restrict__ cnt, int* __restrict__ idxl, float* __restrict__ cw)
{
    const int token = blockIdx.x * 4 + (threadIdx.x >> 6);
    const int lane  = threadIdx.x & 63;
    const float* xr = x1 + (size_t)token * DM;
    float v[8];
#pragma unroll
    for (int i = 0; i < 8; i++) v[i] = xr[lane*8 + i];
    float s = 0.f, sq = 0.f;
#pragma unroll
    for (int i = 0; i < 8; i++) { s += v[i]; sq += v[i]*v[i]; }
#pragma unroll
    for (int o = 1; o < 64; o <<= 1) { s += __shfl_xor(s, o); sq += __shfl_xor(sq, o); }
    float m = s * (1.0f/DM);
    float rstd = rsqrtf(sq*(1.0f/DM) - m*m + 1e-5f);
    float xn[8];
#pragma unroll
    for (int i = 0; i < 8; i++)
        xn[i] = (v[i]-m)*rstd*g[lane*8+i] + b[lane*8+i];
    float logit[8];
#pragma unroll
    for (int e = 0; e < 8; e++) {
        float t = 0.f;
#pragma unroll
        for (int i = 0; i < 8; i++) t += xn[i] * gw[e*DM + lane*8 + i];
#pragma unroll
        for (int o = 1; o < 64; o <<= 1) t += __shfl_xor(t, o);
        logit[e] = t + gb[e];
    }
    if (lane == 0) {
        float mx = -1e30f;
        for (int e = 0; e < 8; e++) mx = fmaxf(mx, logit[e]);
        float den = 0.f, p[8];
        for (int e = 0; e < 8; e++) { p[e] = __expf(logit[e] - mx); den += p[e]; }
        for (int e = 0; e < 8; e++) p[e] /= den;
        int i1 = 0;
        for (int e = 1; e < 8; e++) if (p[e] > p[i1]) i1 = e;
        int i2 = -1;
        for (int e = 0; e < 8; e++) { if (e == i1) continue; if (i2 < 0 || p[e] > p[i2]) i2 = e; }
        int s1 = atomicAdd(&cnt[i1], 1);
        idxl[i1*SQ + s1] = token;  cw[i1*SQ + s1] = p[i1];
        int s2 = atomicAdd(&cnt[i2], 1);
        idxl[i2*SQ + s2] = token;  cw[i2*SQ + s2] = p[i2];
    }
}

// fp32 weight -> split bf16 pair (truncation split)
__global__ __launch_bounds__(256) void cvt_split_w(
    const float* __restrict__ w, u16* __restrict__ wh, u16* __restrict__ wl, int n)
{
    int i = blockIdx.x * 256 + threadIdx.x;
    if (i < n) {
        u16 h, l;
        tsplit(w[i], h, l);
        wh[i] = h;
        wl[i] = l;
    }
}

__global__ __launch_bounds__(256) void init_out(
    const float* __restrict__ x1, float* __restrict__ out)
{
    int i = blockIdx.x * 256 + threadIdx.x;   // float4 index
    ((float4*)out)[i] = ((const float4*)x1)[i];
}

__global__ __launch_bounds__(256) void sentinel_kernel(float* out, float v, int n)
{
    int i = blockIdx.x * 256 + threadIdx.x;
    if (i < n) out[i] = v;
}
__global__ __launch_bounds__(256) void scrub_kernel(float* out, int n)
{
    int i = blockIdx.x * 256 + threadIdx.x;
    if (i < n) { float v = out[i]; if (!isfinite(v)) out[i] = 777.0f; }
}

// ===========================================================================
extern "C" void kernel_launch(void* const* d_in, const int* in_sizes, int n_in,
                              void* d_out, int out_size, void* d_ws, size_t ws_size,
                              hipStream_t stream)
{
    const float* src        = (const float*)d_in[0];
    const float* in_proj_w  = (const float*)d_in[1];
    const float* in_proj_b  = (const float*)d_in[2];
    const float* out_proj_w = (const float*)d_in[3];
    const float* out_proj_b = (const float*)d_in[4];
    const float* ln1_g      = (const float*)d_in[5];
    const float* ln1_b      = (const float*)d_in[6];
    const float* ln2_g      = (const float*)d_in[7];
    const float* ln2_b      = (const float*)d_in[8];
    const float* gate_w     = (const float*)d_in[9];
    const float* gate_b     = (const float*)d_in[10];
    const float* w1         = (const float*)d_in[11];
    const float* b1         = (const float*)d_in[12];
    const float* w2         = (const float*)d_in[13];
    const float* b2         = (const float*)d_in[14];
    const float* wo         = (const float*)d_in[15];
    const float* bo         = (const float*)d_in[16];
    float* out = (float*)d_out;

    const size_t MB = (size_t)1 << 20;
    const size_t ROUTE = 512 * 1024;
    const size_t NEED = ROUTE + 44 * MB;     // peak 44.5 MiB (proven fits)
    if (ws_size < NEED) {
        sentinel_kernel<<<(SQ*DM)/256, 256, 0, stream>>>(out, 333.0f, SQ*DM);
        return;
    }

    char* ws = (char*)d_ws;
    int*   cnt  = (int*)ws;                          // 8 ints
    int*   idxl = (int*)(ws + 1024);                 // 128 KiB
    float* cw   = (float*)(ws + 1024 + 128*1024);    // 128 KiB
    char*  base = ws + ROUTE;
    // phase-reused regions (MiB offsets from base):
    u16* xln1h = (u16*)(base);            // [0,4)   A  -> attnh (B)
    u16* xln1l = (u16*)(base + 4*MB);     // [4,8)   A  -> attnl (B)
    u16* attnh = (u16*)(base);
    u16* attnl = (u16*)(base + 4*MB);
    u16* qkvh  = (u16*)(base + 8*MB);     // [8,20)  A,B
    u16* qkvl  = (u16*)(base + 20*MB);    // [20,32) A,B
    float* x1  = (float*)(base + 8*MB);   // [8,16)  C (qkv dead after flash)
    u16* vth   = (u16*)(base + 32*MB);    // [32,36) A,B
    u16* vtl   = (u16*)(base + 36*MB);    // [36,40) A,B
    u16* xln2  = (u16*)(base + 36*MB);    // [36,40) C (vtl dead)
    u16* Hbuf  = (u16*)(base);            // [0,36)  D (9216 x 2048 bf16)
    u16* wph   = (u16*)(base + 40*MB);            // [40,41.5) in_proj hi
    u16* wpl   = (u16*)(base + 40*MB + 1536*1024);// [41.5,43) in_proj lo
    u16* woh   = (u16*)(base + 43*MB);            // [43,43.5) out_proj hi
    u16* wol   = (u16*)(base + 43*MB + 512*1024); // [43.5,44) out_proj lo

    // ---- weight prep ----
    cvt_split_w<<<(3*DM*DM)/256, 256, 0, stream>>>(in_proj_w,  wph, wpl, 3*DM*DM);
    cvt_split_w<<<(DM*DM)/256,   256, 0, stream>>>(out_proj_w, woh, wol, DM*DM);

    // ---- attention path (emulated fp32) ----
    ln1_split<<<SQ, 256, 0, stream>>>(src, ln1_g, ln1_b, xln1h, xln1l);
    gemm_split<<<dim3(32, 12), 256, 0, stream>>>(
        xln1h, xln1l, DM, wph, wpl, DM, SQ, 3*DM, DM,
        in_proj_b, nullptr, 0, qkvh, qkvl, nullptr, 3*DM, 0);
    transpose_v2<<<dim3(SQ/64, DM/64), 256, 0, stream>>>(qkvh, qkvl, vth, vtl);
    flash_attn<<<dim3(SQ/64, NH), 256, 0, stream>>>(qkvh, qkvl, vth, vtl, attnh, attnl);
    gemm_split<<<dim3(32, 4), 256, 0, stream>>>(          // x1 = src + attn@Wo^T+b
        attnh, attnl, DM, woh, wol, DM, SQ, DM, DM,
        out_proj_b, src, DM, nullptr, nullptr, x1, DM, 1);

    // ---- MoE (sparse top-2, all experts concurrent) ----
    ln_kernel<<<SQ, 256, 0, stream>>>(x1, ln2_g, ln2_b, xln2, cnt);
    gate_route<<<SQ/4, 256, 0, stream>>>(x1, ln2_g, ln2_b, gate_w, gate_b,
                                         cnt, idxl, cw);
    init_out<<<(SQ*DM/4)/256, 256, 0, stream>>>(x1, out);   // last read of x1
    moe12_all<<<dim3(72, 16), 256, 0, stream>>>(            // H (overwrites [0,36M))
        xln2, DM, idxl, cnt, w1, b1, w2, b2, Hbuf);
    moe_y_all<<<dim3(72, 4), 256, 0, stream>>>(
        Hbuf, wo, bo, idxl, cw, cnt, out);

    scrub_kernel<<<(SQ*DM)/256, 256, 0, stream>>>(out, SQ*DM);
}

// Round 8
// 922.752 us; speedup vs baseline: 1.1424x; 1.1424x over previous
//
#include <hip/hip_runtime.h>
#include <hip/hip_bf16.h>
#include <math.h>

// S=4096, D=512, H=8, hd=64, F=2048, E=8, top-2. I/O fp32.
// Attention path: split-bf16 (hi+lo, 3-MFMA) emulated fp32 => fp32-faithful
// routing. MoE: sparse top-2, all experts in one launch, atomic scatter-add.
// R7 lesson: NO register arrays live across the tile body (spills -> 600MB
// HBM writes). Staging loads must be consumed immediately.
#define SQ   4096
#define DM   512
#define NH   8
#define HDIM 64
#define FF   2048
#define NE   8

typedef unsigned short u16;
typedef unsigned int   u32;
typedef __attribute__((ext_vector_type(8))) __bf16 bf16x8;
typedef __attribute__((ext_vector_type(4))) float  f32x4;

__device__ __forceinline__ float bf2f(u16 v) {
    union { u32 i; float f; } c; c.i = ((u32)v) << 16; return c.f;
}
__device__ __forceinline__ u16 f2bf(float f) {  // RNE
    union { float f; u32 i; } c; c.f = f; u32 u = c.i;
    return (u16)((u + 0x7fffu + ((u >> 16) & 1u)) >> 16);
}
// Truncation split: v = hi + r exactly, lo = trunc-bf16(r). 4 VALU ops.
__device__ __forceinline__ void tsplit(float v, u16& hi, u16& lo) {
    u32 vb = __float_as_uint(v);
    u32 hb = vb & 0xFFFF0000u;
    float r = v - __uint_as_float(hb);
    hi = (u16)(hb >> 16);
    lo = (u16)(__float_as_uint(r) >> 16);
}

#define BM 128
#define BN 128
#define BK 32
#define BKP 40   // padded LDS row stride (2-way on frag reads -> free)

// ===========================================================================
// Split-bf16 GEMM: C = (Ahi+Alo)@(Bhi+Blo)^T + bias. 3 MFMAs (hh+hl+lh).
// mode 0: split bf16 pair out. mode 1: fp32 out (+resid).
// ===========================================================================
__global__ __launch_bounds__(256) void gemm_split(
    const u16* __restrict__ Ahi, const u16* __restrict__ Alo, int lda,
    const u16* __restrict__ Bhi, const u16* __restrict__ Blo, int ldb,
    int M, int N, int K,
    const float* __restrict__ bias,
    const float* __restrict__ resid, int ldres,
    u16* __restrict__ Chi, u16* __restrict__ Clo,
    float* __restrict__ Cf, int ldc, int mode)
{
    __shared__ __align__(16) u16 Ash[BM * BKP], Asl[BM * BKP];
    __shared__ __align__(16) u16 Bsh[BN * BKP], Bsl[BN * BKP];
    const int tid  = threadIdx.x;
    const int wave = tid >> 6;
    const int lane = tid & 63;
    const int quad = lane >> 4;
    const int l16  = lane & 15;
    const int bm = blockIdx.x * BM;
    const int bn = blockIdx.y * BN;
    const int wm = (wave & 1) * 64;
    const int wn = (wave >> 1) * 64;

    f32x4 acc[4][4];
#pragma unroll
    for (int i = 0; i < 4; i++)
#pragma unroll
        for (int j = 0; j < 4; j++)
#pragma unroll
            for (int r = 0; r < 4; r++) acc[i][j][r] = 0.0f;

    for (int k0 = 0; k0 < K; k0 += BK) {
#pragma unroll
        for (int i = 0; i < 2; i++) {
            int c = tid + i * 256;
            int row = c >> 2;
            int col = (c & 3) << 3;
            int ga = bm + row, gb2 = bn + row;
            uint4 vah = make_uint4(0u,0u,0u,0u), val = vah, vbh = vah, vbl = vah;
            if (ga < M) {
                vah = *(const uint4*)(Ahi + (size_t)ga * lda + k0 + col);
                val = *(const uint4*)(Alo + (size_t)ga * lda + k0 + col);
            }
            if (gb2 < N) {
                vbh = *(const uint4*)(Bhi + (size_t)gb2 * ldb + k0 + col);
                vbl = *(const uint4*)(Blo + (size_t)gb2 * ldb + k0 + col);
            }
            *(uint4*)(Ash + row * BKP + col) = vah;
            *(uint4*)(Asl + row * BKP + col) = val;
            *(uint4*)(Bsh + row * BKP + col) = vbh;
            *(uint4*)(Bsl + row * BKP + col) = vbl;
        }
        __syncthreads();
        bf16x8 ah[4], al[4], bh[4], bl[4];
#pragma unroll
        for (int i = 0; i < 4; i++) {
            ah[i] = *(const bf16x8*)(Ash + (wm + i * 16 + l16) * BKP + quad * 8);
            al[i] = *(const bf16x8*)(Asl + (wm + i * 16 + l16) * BKP + quad * 8);
        }
#pragma unroll
        for (int j = 0; j < 4; j++) {
            bh[j] = *(const bf16x8*)(Bsh + (wn + j * 16 + l16) * BKP + quad * 8);
            bl[j] = *(const bf16x8*)(Bsl + (wn + j * 16 + l16) * BKP + quad * 8);
        }
#pragma unroll
        for (int i = 0; i < 4; i++)
#pragma unroll
            for (int j = 0; j < 4; j++) {
                acc[i][j] = __builtin_amdgcn_mfma_f32_16x16x32_bf16(ah[i], bh[j], acc[i][j], 0,0,0);
                acc[i][j] = __builtin_amdgcn_mfma_f32_16x16x32_bf16(ah[i], bl[j], acc[i][j], 0,0,0);
                acc[i][j] = __builtin_amdgcn_mfma_f32_16x16x32_bf16(al[i], bh[j], acc[i][j], 0,0,0);
            }
        __syncthreads();
    }

#pragma unroll
    for (int i = 0; i < 4; i++)
#pragma unroll
        for (int j = 0; j < 4; j++)
#pragma unroll
            for (int r = 0; r < 4; r++) {
                int row = bm + wm + i * 16 + quad * 4 + r;
                int col = bn + wn + j * 16 + l16;
                if (row >= M || col >= N) continue;
                float v = acc[i][j][r] + (bias ? bias[col] : 0.0f);
                size_t idx = (size_t)row * ldc + col;
                if (mode == 0) {
                    u16 hb, lb;
                    tsplit(v, hb, lb);
                    Chi[idx] = hb;
                    Clo[idx] = lb;
                } else {
                    if (resid) v += resid[(size_t)row * ldres + col];
                    Cf[idx] = v;
                }
            }
}

// Inline expert lookup from cnt (128-aligned packing).
__device__ __forceinline__ int find_expert(const int* __restrict__ cnt,
                                           int bmg, int& bml, int& obase)
{
    int a = 0;
#pragma unroll
    for (int e = 0; e < NE; e++) {
        int pad = ((cnt[e] + 127) >> 7) << 7;
        if (bmg < a + pad) { bml = bmg - a; obase = a; return e; }
        a += pad;
    }
    return -1;
}

// ===========================================================================
// MoE all-expert fused w1/w2 GEMM: h = silu(x@w1^T+b1)*(x@w2^T+b2)
// grid (72, 16). A rows gathered via idxl; B staged fp32->bf16 inline.
// ===========================================================================
__global__ __launch_bounds__(256) void moe12_all(
    const u16* __restrict__ A, int lda,
    const int* __restrict__ idxl, const int* __restrict__ cnt,
    const float* __restrict__ w1, const float* __restrict__ b1,
    const float* __restrict__ w2, const float* __restrict__ b2,
    u16* __restrict__ H)
{
    const int bmg = blockIdx.x * BM;
    int bml, obase;
    int e = find_expert(cnt, bmg, bml, obase);
    if (e < 0) return;
    const int M = cnt[e];
    if (bml >= M) return;
    const float* B1 = w1 + (size_t)e * FF * DM;
    const float* B2 = w2 + (size_t)e * FF * DM;
    const int*   rl = idxl + e * SQ;

    __shared__ __align__(16) u16 As[BM * BKP], Bs1[BN * BKP], Bs2[BN * BKP];
    const int tid  = threadIdx.x;
    const int wave = tid >> 6;
    const int lane = tid & 63;
    const int quad = lane >> 4;
    const int l16  = lane & 15;
    const int bn = blockIdx.y * BN;
    const int wm = (wave & 1) * 64;
    const int wn = (wave >> 1) * 64;

    f32x4 acc1[4][4], acc2[4][4];
#pragma unroll
    for (int i = 0; i < 4; i++)
#pragma unroll
        for (int j = 0; j < 4; j++)
#pragma unroll
            for (int r = 0; r < 4; r++) { acc1[i][j][r] = 0.0f; acc2[i][j][r] = 0.0f; }

    for (int k0 = 0; k0 < DM; k0 += BK) {
#pragma unroll
        for (int i = 0; i < 2; i++) {
            int c = tid + i * 256;
            int row = c >> 2;
            int col = (c & 3) << 3;
            uint4 va = make_uint4(0u,0u,0u,0u);
            int lr = bml + row;
            if (lr < M) {
                int ar = rl[lr];
                va = *(const uint4*)(A + (size_t)ar * lda + k0 + col);
            }
            *(uint4*)(As + row * BKP + col) = va;
        }
#pragma unroll
        for (int i = 0; i < 4; i++) {
            int c = tid + i * 256;
            int row = c >> 3;
            int col = (c & 7) << 2;
            float4 v1 = *(const float4*)(B1 + (size_t)(bn + row) * DM + k0 + col);
            float4 v2 = *(const float4*)(B2 + (size_t)(bn + row) * DM + k0 + col);
            ushort4 h1, h2;
            h1.x = f2bf(v1.x); h1.y = f2bf(v1.y); h1.z = f2bf(v1.z); h1.w = f2bf(v1.w);
            h2.x = f2bf(v2.x); h2.y = f2bf(v2.y); h2.z = f2bf(v2.z); h2.w = f2bf(v2.w);
            *(ushort4*)(Bs1 + row * BKP + col) = h1;
            *(ushort4*)(Bs2 + row * BKP + col) = h2;
        }
        __syncthreads();
        bf16x8 af[4], b1f[4], b2f[4];
#pragma unroll
        for (int i = 0; i < 4; i++)
            af[i] = *(const bf16x8*)(As + (wm + i * 16 + l16) * BKP + quad * 8);
#pragma unroll
        for (int j = 0; j < 4; j++) {
            b1f[j] = *(const bf16x8*)(Bs1 + (wn + j * 16 + l16) * BKP + quad * 8);
            b2f[j] = *(const bf16x8*)(Bs2 + (wn + j * 16 + l16) * BKP + quad * 8);
        }
#pragma unroll
        for (int i = 0; i < 4; i++)
#pragma unroll
            for (int j = 0; j < 4; j++) {
                acc1[i][j] = __builtin_amdgcn_mfma_f32_16x16x32_bf16(af[i], b1f[j], acc1[i][j], 0,0,0);
                acc2[i][j] = __builtin_amdgcn_mfma_f32_16x16x32_bf16(af[i], b2f[j], acc2[i][j], 0,0,0);
            }
        __syncthreads();
    }

#pragma unroll
    for (int i = 0; i < 4; i++)
#pragma unroll
        for (int j = 0; j < 4; j++)
#pragma unroll
            for (int r = 0; r < 4; r++) {
                int rowl = bml + wm + i * 16 + quad * 4 + r;
                if (rowl >= M) continue;
                int col = bn + wn + j * 16 + l16;
                float g1 = acc1[i][j][r] + b1[e * FF + col];
                float g2 = acc2[i][j][r] + b2[e * FF + col];
                float s  = g1 / (1.0f + __expf(-g1));
                H[(size_t)(obase + rowl) * FF + col] = f2bf(s * g2);
            }
}

// ===========================================================================
// MoE all-expert down-proj: out[tok] += cw*(h@wo^T + bo). grid (72, 4).
// ===========================================================================
__global__ __launch_bounds__(256) void moe_y_all(
    const u16* __restrict__ H,
    const float* __restrict__ wo, const float* __restrict__ bo,
    const int* __restrict__ idxl, const float* __restrict__ cw,
    const int* __restrict__ cnt,
    float* __restrict__ out)
{
    const int bmg = blockIdx.x * BM;
    int bml, obase;
    int e = find_expert(cnt, bmg, bml, obase);
    if (e < 0) return;
    const int M = cnt[e];
    if (bml >= M) return;
    const float* B = wo + (size_t)e * DM * FF;

    __shared__ __align__(16) u16 As[BM * BKP], Bs[BN * BKP];
    const int tid  = threadIdx.x;
    const int wave = tid >> 6;
    const int lane = tid & 63;
    const int quad = lane >> 4;
    const int l16  = lane & 15;
    const int bn = blockIdx.y * BN;
    const int wm = (wave & 1) * 64;
    const int wn = (wave >> 1) * 64;

    f32x4 acc[4][4];
#pragma unroll
    for (int i = 0; i < 4; i++)
#pragma unroll
        for (int j = 0; j < 4; j++)
#pragma unroll
            for (int r = 0; r < 4; r++) acc[i][j][r] = 0.0f;

    for (int k0 = 0; k0 < FF; k0 += BK) {
#pragma unroll
        for (int i = 0; i < 2; i++) {
            int c = tid + i * 256;
            int row = c >> 2;
            int col = (c & 3) << 3;
            uint4 va = *(const uint4*)(H + (size_t)(bmg + row) * FF + k0 + col);
            *(uint4*)(As + row * BKP + col) = va;
        }
#pragma unroll
        for (int i = 0; i < 4; i++) {
            int c = tid + i * 256;
            int row = c >> 3;
            int col = (c & 7) << 2;
            float4 v = *(const float4*)(B + (size_t)(bn + row) * FF + k0 + col);
            ushort4 h;
            h.x = f2bf(v.x); h.y = f2bf(v.y); h.z = f2bf(v.z); h.w = f2bf(v.w);
            *(ushort4*)(Bs + row * BKP + col) = h;
        }
        __syncthreads();
        bf16x8 af[4], bf[4];
#pragma unroll
        for (int i = 0; i < 4; i++)
            af[i] = *(const bf16x8*)(As + (wm + i * 16 + l16) * BKP + quad * 8);
#pragma unroll
        for (int j = 0; j < 4; j++)
            bf[j] = *(const bf16x8*)(Bs + (wn + j * 16 + l16) * BKP + quad * 8);
#pragma unroll
        for (int i = 0; i < 4; i++)
#pragma unroll
            for (int j = 0; j < 4; j++)
                acc[i][j] = __builtin_amdgcn_mfma_f32_16x16x32_bf16(af[i], bf[j], acc[i][j], 0,0,0);
        __syncthreads();
    }

#pragma unroll
    for (int i = 0; i < 4; i++)
#pragma unroll
        for (int j = 0; j < 4; j++)
#pragma unroll
            for (int r = 0; r < 4; r++) {
                int rowl = bml + wm + i * 16 + quad * 4 + r;
                if (rowl >= M) continue;
                int col = bn + wn + j * 16 + l16;
                int tok = idxl[e * SQ + rowl];
                float wgt = cw[e * SQ + rowl];
                atomicAdd(out + (size_t)tok * DM + col,
                          wgt * (acc[i][j][r] + bo[e * DM + col]));
            }
}

// ===========================================================================
// Flash attention, split precision. 64-row Q tiles, grid (64, 8), 256 thr.
// Direct global->LDS staging (NO long-lived register prefetch — spills).
// Raw-domain max + fma-folded exp2; truncation hi/lo splits.
// LDS: K/V stride 72; P stride 68 -> total 54272 B -> 3 blocks/CU.
// ===========================================================================
#define KP  72
#define KPP 68
#define SCL 0.18033688011112042f   // 0.125 * log2(e)
__global__ __launch_bounds__(256) void flash_attn(
    const u16* __restrict__ qh, const u16* __restrict__ ql,   // [4096,1536]
    const u16* __restrict__ vth, const u16* __restrict__ vtl, // [512,4096]
    u16* __restrict__ oh, u16* __restrict__ ol)               // [4096,512]
{
    __shared__ __align__(16) u16 Ksh[64*KP], Ksl[64*KP], Vsh[64*KP], Vsl[64*KP];
    __shared__ __align__(16) u16 Psh[4][16*KPP], Psl[4][16*KPP];
    const int tid  = threadIdx.x;
    const int wave = tid >> 6;
    const int lane = tid & 63;
    const int quad = lane >> 4;
    const int l16  = lane & 15;
    const int h    = blockIdx.y;
    const int qbase = blockIdx.x * 64 + wave * 16;

    bf16x8 aqh[2], aql[2];
#pragma unroll
    for (int kk = 0; kk < 2; kk++) {
        size_t off = (size_t)(qbase + l16) * (3*DM) + h*HDIM + kk*32 + quad*8;
        aqh[kk] = *(const bf16x8*)(qh + off);
        aql[kk] = *(const bf16x8*)(ql + off);
    }

    float m_[4], l_[4];
    f32x4 o_[4];
#pragma unroll
    for (int r = 0; r < 4; r++) { m_[r] = -1e30f; l_[r] = 0.0f; }
#pragma unroll
    for (int nd = 0; nd < 4; nd++)
#pragma unroll
        for (int r = 0; r < 4; r++) o_[nd][r] = 0.0f;

    for (int jt = 0; jt < SQ / 64; jt++) {
        // direct staging: loads consumed immediately (short live ranges)
#pragma unroll
        for (int i = 0; i < 2; i++) {
            int c = tid + i * 256;
            int r = c >> 3;
            int co = (c & 7) << 3;
            size_t koff = (size_t)(jt*64 + r) * (3*DM) + DM + h*HDIM + co;
            size_t voff = (size_t)(h*HDIM + r) * SQ + jt*64 + co;
            *(uint4*)(Ksh + r*KP + co) = *(const uint4*)(qh + koff);
            *(uint4*)(Ksl + r*KP + co) = *(const uint4*)(ql + koff);
            *(uint4*)(Vsh + r*KP + co) = *(const uint4*)(vth + voff);
            *(uint4*)(Vsl + r*KP + co) = *(const uint4*)(vtl + voff);
        }
        __syncthreads();

        f32x4 s[4];
#pragma unroll
        for (int jn = 0; jn < 4; jn++) {
            f32x4 z;
#pragma unroll
            for (int r = 0; r < 4; r++) z[r] = 0.0f;
#pragma unroll
            for (int kk = 0; kk < 2; kk++) {
                bf16x8 kh = *(const bf16x8*)(Ksh + (jn*16 + l16)*KP + kk*32 + quad*8);
                bf16x8 kl = *(const bf16x8*)(Ksl + (jn*16 + l16)*KP + kk*32 + quad*8);
                z = __builtin_amdgcn_mfma_f32_16x16x32_bf16(aqh[kk], kh, z, 0,0,0);
                z = __builtin_amdgcn_mfma_f32_16x16x32_bf16(aqh[kk], kl, z, 0,0,0);
                z = __builtin_amdgcn_mfma_f32_16x16x32_bf16(aql[kk], kh, z, 0,0,0);
            }
            s[jn] = z;   // raw scores (scale folded into exp2 below)
        }

        float mx[4], al2[4], rs[4], nscl[4];
#pragma unroll
        for (int r = 0; r < 4; r++)
            mx[r] = fmaxf(fmaxf(s[0][r], s[1][r]), fmaxf(s[2][r], s[3][r]));
#pragma unroll
        for (int r = 0; r < 4; r++) {
#pragma unroll
            for (int o2 = 1; o2 < 16; o2 <<= 1)
                mx[r] = fmaxf(mx[r], __shfl_xor(mx[r], o2));
            float nm = fmaxf(m_[r], mx[r]);
            al2[r] = exp2f((m_[r] - nm) * SCL);
            m_[r] = nm;
            nscl[r] = nm * SCL;
            rs[r] = 0.0f;
        }
#pragma unroll
        for (int jn = 0; jn < 4; jn++)
#pragma unroll
            for (int r = 0; r < 4; r++) {
                float p = exp2f(fmaf(s[jn][r], SCL, -nscl[r]));
                s[jn][r] = p;
                rs[r] += p;
            }
#pragma unroll
        for (int r = 0; r < 4; r++) {
#pragma unroll
            for (int o2 = 1; o2 < 16; o2 <<= 1)
                rs[r] += __shfl_xor(rs[r], o2);
            l_[r] = l_[r] * al2[r] + rs[r];
        }
#pragma unroll
        for (int nd = 0; nd < 4; nd++)
#pragma unroll
            for (int r = 0; r < 4; r++) o_[nd][r] *= al2[r];
#pragma unroll
        for (int jn = 0; jn < 4; jn++)
#pragma unroll
            for (int r = 0; r < 4; r++) {
                u16 ph, pl;
                tsplit(s[jn][r], ph, pl);
                int pidx = (quad*4 + r)*KPP + jn*16 + l16;
                Psh[wave][pidx] = ph;
                Psl[wave][pidx] = pl;
            }
        // no barrier: Ps is wave-private; per-wave DS ops execute in order

        bf16x8 php[2], plp[2];
#pragma unroll
        for (int kk = 0; kk < 2; kk++) {
            php[kk] = *(const bf16x8*)(Psh[wave] + l16*KPP + kk*32 + quad*8);
            plp[kk] = *(const bf16x8*)(Psl[wave] + l16*KPP + kk*32 + quad*8);
        }
#pragma unroll
        for (int nd = 0; nd < 4; nd++) {
#pragma unroll
            for (int kk = 0; kk < 2; kk++) {
                bf16x8 vh = *(const bf16x8*)(Vsh + (nd*16 + l16)*KP + kk*32 + quad*8);
                bf16x8 vl = *(const bf16x8*)(Vsl + (nd*16 + l16)*KP + kk*32 + quad*8);
                o_[nd] = __builtin_amdgcn_mfma_f32_16x16x32_bf16(php[kk], vh, o_[nd], 0,0,0);
                o_[nd] = __builtin_amdgcn_mfma_f32_16x16x32_bf16(php[kk], vl, o_[nd], 0,0,0);
                o_[nd] = __builtin_amdgcn_mfma_f32_16x16x32_bf16(plp[kk], vh, o_[nd], 0,0,0);
            }
        }
        __syncthreads();   // before next tile overwrites Ks/Vs
    }

#pragma unroll
    for (int nd = 0; nd < 4; nd++)
#pragma unroll
        for (int r = 0; r < 4; r++) {
            int row = qbase + quad*4 + r;
            int col = h*HDIM + nd*16 + l16;
            float w = o_[nd][r] / l_[r];
            u16 hb, lb;
            tsplit(w, hb, lb);
            oh[(size_t)row * DM + col] = hb;
            ol[(size_t)row * DM + col] = lb;
        }
}

// LN1: fp32 in -> split bf16 pair out.
__global__ __launch_bounds__(256) void ln1_split(
    const float* __restrict__ x, const float* __restrict__ g,
    const float* __restrict__ b, u16* __restrict__ ohi, u16* __restrict__ olo)
{
    const int row = blockIdx.x;
    const int tid = threadIdx.x;
    float v0 = x[(size_t)row * DM + tid];
    float v1 = x[(size_t)row * DM + tid + 256];
    float s = v0 + v1, sq = v0*v0 + v1*v1;
#pragma unroll
    for (int o = 1; o < 64; o <<= 1) { s += __shfl_xor(s, o); sq += __shfl_xor(sq, o); }
    __shared__ float ss[4], ssq[4];
    if ((tid & 63) == 0) { ss[tid>>6] = s; ssq[tid>>6] = sq; }
    __syncthreads();
    s  = ss[0]+ss[1]+ss[2]+ss[3];
    sq = ssq[0]+ssq[1]+ssq[2]+ssq[3];
    float m = s * (1.0f/DM);
    float rstd = rsqrtf(sq*(1.0f/DM) - m*m + 1e-5f);
    float y0 = (v0-m)*rstd*g[tid]     + b[tid];
    float y1 = (v1-m)*rstd*g[tid+256] + b[tid+256];
    u16 h0, l0, h1, l1;
    tsplit(y0, h0, l0);
    tsplit(y1, h1, l1);
    ohi[(size_t)row*DM + tid]       = h0;  olo[(size_t)row*DM + tid]       = l0;
    ohi[(size_t)row*DM + tid + 256] = h1;  olo[(size_t)row*DM + tid + 256] = l1;
}

// LN2: fp32 in -> plain bf16 out. Block 0 also zeroes the routing counters.
__global__ __launch_bounds__(256) void ln_kernel(
    const float* __restrict__ x, const float* __restrict__ g,
    const float* __restrict__ b, u16* __restrict__ out, int* __restrict__ cnt)
{
    const int row = blockIdx.x;
    const int tid = threadIdx.x;
    if (row == 0 && tid < NE) cnt[tid] = 0;
    float v0 = x[(size_t)row * DM + tid];
    float v1 = x[(size_t)row * DM + tid + 256];
    float s = v0 + v1, sq = v0*v0 + v1*v1;
#pragma unroll
    for (int o = 1; o < 64; o <<= 1) { s += __shfl_xor(s, o); sq += __shfl_xor(sq, o); }
    __shared__ float ss[4], ssq[4];
    if ((tid & 63) == 0) { ss[tid>>6] = s; ssq[tid>>6] = sq; }
    __syncthreads();
    s  = ss[0]+ss[1]+ss[2]+ss[3];
    sq = ssq[0]+ssq[1]+ssq[2]+ssq[3];
    float m = s * (1.0f/DM);
    float rstd = rsqrtf(sq*(1.0f/DM) - m*m + 1e-5f);
    out[(size_t)row*DM + tid]       = f2bf((v0-m)*rstd*g[tid]     + b[tid]);
    out[(size_t)row*DM + tid + 256] = f2bf((v1-m)*rstd*g[tid+256] + b[tid+256]);
}

// Coalesced V transpose via LDS 64x64 tiles (pad 66: both phases conflict-free)
__global__ __launch_bounds__(256) void transpose_v2(
    const u16* __restrict__ qh, const u16* __restrict__ ql,
    u16* __restrict__ vth, u16* __restrict__ vtl)
{
    __shared__ u16 Th[64 * 66], Tl[64 * 66];
    const int t0  = blockIdx.x * 64;
    const int hd0 = blockIdx.y * 64;
    const int tid = threadIdx.x;
#pragma unroll
    for (int k = 0; k < 16; k++) {
        int idx = tid + k * 256;
        int r = idx >> 6, j = idx & 63;
        size_t src = (size_t)(t0 + r) * (3*DM) + 2*DM + hd0 + j;
        Th[r * 66 + j] = qh[src];
        Tl[r * 66 + j] = ql[src];
    }
    __syncthreads();
#pragma unroll
    for (int k = 0; k < 16; k++) {
        int idx = tid + k * 256;
        int r = idx >> 6, c2 = idx & 63;
        size_t dst = (size_t)(hd0 + r) * SQ + t0 + c2;
        vth[dst] = Th[c2 * 66 + r];
        vtl[dst] = Tl[c2 * 66 + r];
    }
}

// Gate (own fp32 LN2) + top-2 compaction into per-expert lists.
__global__ __launch_bounds__(256) void gate_route(
    const float* __restrict__ x1, const float* __restrict__ g,
    const float* __restrict__ b, const float* __restrict__ gw,
    const float* __restrict__ gb,
    int* __restrict__ cnt, int* __restrict__ idxl, float* __restrict__ cw)
{
    const int token = blockIdx.x * 4 + (threadIdx.x >> 6);
    const int lane  = threadIdx.x & 63;
    const float* xr = x1 + (size_t)token * DM;
    float v[8];
#pragma unroll
    for (int i = 0; i < 8; i++) v[i] = xr[lane*8 + i];
    float s = 0.f, sq = 0.f;
#pragma unroll
    for (int i = 0; i < 8; i++) { s += v[i]; sq += v[i]*v[i]; }
#pragma unroll
    for (int o = 1; o < 64; o <<= 1) { s += __shfl_xor(s, o); sq += __shfl_xor(sq, o); }
    float m = s * (1.0f/DM);
    float rstd = rsqrtf(sq*(1.0f/DM) - m*m + 1e-5f);
    float xn[8];
#pragma unroll
    for (int i = 0; i < 8; i++)
        xn[i] = (v[i]-m)*rstd*g[lane*8+i] + b[lane*8+i];
    float logit[8];
#pragma unroll
    for (int e = 0; e < 8; e++) {
        float t = 0.f;
#pragma unroll
        for (int i = 0; i < 8; i++) t += xn[i] * gw[e*DM + lane*8 + i];
#pragma unroll
        for (int o = 1; o < 64; o <<= 1) t += __shfl_xor(t, o);
        logit[e] = t + gb[e];
    }
    if (lane == 0) {
        float mx = -1e30f;
        for (int e = 0; e < 8; e++) mx = fmaxf(mx, logit[e]);
        float den = 0.f, p[8];
        for (int e = 0; e < 8; e++) { p[e] = __expf(logit[e] - mx); den += p[e]; }
        for (int e = 0; e < 8; e++) p[e] /= den;
        int i1 = 0;
        for (int e = 1; e < 8; e++) if (p[e] > p[i1]) i1 = e;
        int i2 = -1;
        for (int e = 0; e < 8; e++) { if (e == i1) continue; if (i2 < 0 || p[e] > p[i2]) i2 = e; }
        int s1 = atomicAdd(&cnt[i1], 1);
        idxl[i1*SQ + s1] = token;  cw[i1*SQ + s1] = p[i1];
        int s2 = atomicAdd(&cnt[i2], 1);
        idxl[i2*SQ + s2] = token;  cw[i2*SQ + s2] = p[i2];
    }
}

// fp32 weight -> split bf16 pair (truncation split)
__global__ __launch_bounds__(256) void cvt_split_w(
    const float* __restrict__ w, u16* __restrict__ wh, u16* __restrict__ wl, int n)
{
    int i = blockIdx.x * 256 + threadIdx.x;
    if (i < n) {
        u16 h, l;
        tsplit(w[i], h, l);
        wh[i] = h;
        wl[i] = l;
    }
}

__global__ __launch_bounds__(256) void init_out(
    const float* __restrict__ x1, float* __restrict__ out)
{
    int i = blockIdx.x * 256 + threadIdx.x;   // float4 index
    ((float4*)out)[i] = ((const float4*)x1)[i];
}

__global__ __launch_bounds__(256) void sentinel_kernel(float* out, float v, int n)
{
    int i = blockIdx.x * 256 + threadIdx.x;
    if (i < n) out[i] = v;
}
__global__ __launch_bounds__(256) void scrub_kernel(float* out, int n)
{
    int i = blockIdx.x * 256 + threadIdx.x;
    if (i < n) { float v = out[i]; if (!isfinite(v)) out[i] = 777.0f; }
}

// ===========================================================================
extern "C" void kernel_launch(void* const* d_in, const int* in_sizes, int n_in,
                              void* d_out, int out_size, void* d_ws, size_t ws_size,
                              hipStream_t stream)
{
    const float* src        = (const float*)d_in[0];
    const float* in_proj_w  = (const float*)d_in[1];
    const float* in_proj_b  = (const float*)d_in[2];
    const float* out_proj_w = (const float*)d_in[3];
    const float* out_proj_b = (const float*)d_in[4];
    const float* ln1_g      = (const float*)d_in[5];
    const float* ln1_b      = (const float*)d_in[6];
    const float* ln2_g      = (const float*)d_in[7];
    const float* ln2_b      = (const float*)d_in[8];
    const float* gate_w     = (const float*)d_in[9];
    const float* gate_b     = (const float*)d_in[10];
    const float* w1         = (const float*)d_in[11];
    const float* b1         = (const float*)d_in[12];
    const float* w2         = (const float*)d_in[13];
    const float* b2         = (const float*)d_in[14];
    const float* wo         = (const float*)d_in[15];
    const float* bo         = (const float*)d_in[16];
    float* out = (float*)d_out;

    const size_t MB = (size_t)1 << 20;
    const size_t ROUTE = 512 * 1024;
    const size_t NEED = ROUTE + 44 * MB;     // peak 44.5 MiB (proven fits)
    if (ws_size < NEED) {
        sentinel_kernel<<<(SQ*DM)/256, 256, 0, stream>>>(out, 333.0f, SQ*DM);
        return;
    }

    char* ws = (char*)d_ws;
    int*   cnt  = (int*)ws;                          // 8 ints
    int*   idxl = (int*)(ws + 1024);                 // 128 KiB
    float* cw   = (float*)(ws + 1024 + 128*1024);    // 128 KiB
    char*  base = ws + ROUTE;
    // phase-reused regions (MiB offsets from base):
    u16* xln1h = (u16*)(base);            // [0,4)   A  -> attnh (B)
    u16* xln1l = (u16*)(base + 4*MB);     // [4,8)   A  -> attnl (B)
    u16* attnh = (u16*)(base);
    u16* attnl = (u16*)(base + 4*MB);
    u16* qkvh  = (u16*)(base + 8*MB);     // [8,20)  A,B
    u16* qkvl  = (u16*)(base + 20*MB);    // [20,32) A,B
    float* x1  = (float*)(base + 8*MB);   // [8,16)  C (qkv dead after flash)
    u16* vth   = (u16*)(base + 32*MB);    // [32,36) A,B
    u16* vtl   = (u16*)(base + 36*MB);    // [36,40) A,B
    u16* xln2  = (u16*)(base + 36*MB);    // [36,40) C (vtl dead)
    u16* Hbuf  = (u16*)(base);            // [0,36)  D (9216 x 2048 bf16)
    u16* wph   = (u16*)(base + 40*MB);            // [40,41.5) in_proj hi
    u16* wpl   = (u16*)(base + 40*MB + 1536*1024);// [41.5,43) in_proj lo
    u16* woh   = (u16*)(base + 43*MB);            // [43,43.5) out_proj hi
    u16* wol   = (u16*)(base + 43*MB + 512*1024); // [43.5,44) out_proj lo

    // ---- weight prep ----
    cvt_split_w<<<(3*DM*DM)/256, 256, 0, stream>>>(in_proj_w,  wph, wpl, 3*DM*DM);
    cvt_split_w<<<(DM*DM)/256,   256, 0, stream>>>(out_proj_w, woh, wol, DM*DM);

    // ---- attention path (emulated fp32) ----
    ln1_split<<<SQ, 256, 0, stream>>>(src, ln1_g, ln1_b, xln1h, xln1l);
    gemm_split<<<dim3(32, 12), 256, 0, stream>>>(
        xln1h, xln1l, DM, wph, wpl, DM, SQ, 3*DM, DM,
        in_proj_b, nullptr, 0, qkvh, qkvl, nullptr, 3*DM, 0);
    transpose_v2<<<dim3(SQ/64, DM/64), 256, 0, stream>>>(qkvh, qkvl, vth, vtl);
    flash_attn<<<dim3(SQ/64, NH), 256, 0, stream>>>(qkvh, qkvl, vth, vtl, attnh, attnl);
    gemm_split<<<dim3(32, 4), 256, 0, stream>>>(          // x1 = src + attn@Wo^T+b
        attnh, attnl, DM, woh, wol, DM, SQ, DM, DM,
        out_proj_b, src, DM, nullptr, nullptr, x1, DM, 1);

    // ---- MoE (sparse top-2, all experts concurrent) ----
    ln_kernel<<<SQ, 256, 0, stream>>>(x1, ln2_g, ln2_b, xln2, cnt);
    gate_route<<<SQ/4, 256, 0, stream>>>(x1, ln2_g, ln2_b, gate_w, gate_b,
                                         cnt, idxl, cw);
    init_out<<<(SQ*DM/4)/256, 256, 0, stream>>>(x1, out);   // last read of x1
    moe12_all<<<dim3(72, 16), 256, 0, stream>>>(            // H (overwrites [0,36M))
        xln2, DM, idxl, cnt, w1, b1, w2, b2, Hbuf);
    moe_y_all<<<dim3(72, 4), 256, 0, stream>>>(
        Hbuf, wo, bo, idxl, cw, cnt, out);

    scrub_kernel<<<(SQ*DM)/256, 256, 0, stream>>>(out, SQ*DM);
}